// Round 1
// baseline (596.284 us; speedup 1.0000x reference)
//
#include <hip/hip_runtime.h>

#define B_SZ  2
#define T_SEQ 2048
#define D_MOD 1024
#define NH    8
#define HD    128

typedef __attribute__((ext_vector_type(8))) short short8;   // 8 x bf16 frag
typedef __attribute__((ext_vector_type(4))) float f32x4;    // mfma accumulator

__device__ __forceinline__ short f2bf(float f) {
  unsigned u = __float_as_uint(f);
  unsigned r = u + 0x7fffu + ((u >> 16) & 1u);   // RNE
  return (short)(r >> 16);
}

// ---------------- decay table: dm[n] = mean_h exp(-theta_h*n) / sqrt(HD) ----
__global__ void decay_kernel(const float* __restrict__ theta,
                             float* __restrict__ dm) {
  int n = blockIdx.x * 256 + threadIdx.x;
  if (n >= T_SEQ) return;
  float nf = (float)n;
  float s = 0.f;
#pragma unroll
  for (int h = 0; h < NH; h++) s += __expf(-theta[h] * nf);
  dm[n] = s * (0.08838834764831845f / 8.0f);  // (1/sqrt(128)) * (1/H)
}

// ---------------- fp32 tiled GEMM: QKV projections ------------------------
// C(4096x1024) = x(4096x1024) @ W, output converted to bf16 in (B,H,T,HD)
__global__ __launch_bounds__(256, 2) void qkv_gemm(
    const float* __restrict__ x, const float* __restrict__ Wq,
    const float* __restrict__ Wk, const float* __restrict__ Wv,
    short* __restrict__ qb, short* __restrict__ kb, short* __restrict__ vb) {
  __shared__ __align__(16) float At[16][132];  // A transposed, +4 pad
  __shared__ __align__(16) float Bt[16][132];
  const int tid = threadIdx.x;
  const int tx = tid & 15, ty = tid >> 4;
  const int row0 = blockIdx.x * 128;
  const int col0 = blockIdx.y * 128;
  const float* __restrict__ W =
      (blockIdx.z == 0) ? Wq : (blockIdx.z == 1) ? Wk : Wv;
  short* __restrict__ dst =
      (blockIdx.z == 0) ? qb : (blockIdx.z == 1) ? kb : vb;

  float acc[8][8];
#pragma unroll
  for (int i = 0; i < 8; i++)
#pragma unroll
    for (int j = 0; j < 8; j++) acc[i][j] = 0.f;

  for (int k0 = 0; k0 < D_MOD; k0 += 16) {
#pragma unroll
    for (int i = 0; i < 2; i++) {
      int s = tid + i * 256;
      int r = s >> 2;
      int kq = (s & 3) << 2;
      float4 av = *(const float4*)(x + (size_t)(row0 + r) * D_MOD + k0 + kq);
      At[kq + 0][r] = av.x; At[kq + 1][r] = av.y;
      At[kq + 2][r] = av.z; At[kq + 3][r] = av.w;
    }
#pragma unroll
    for (int i = 0; i < 2; i++) {
      int s = tid + i * 256;
      int kk = s >> 5;
      int c4 = (s & 31) << 2;
      *(float4*)&Bt[kk][c4] =
          *(const float4*)(W + (size_t)(k0 + kk) * D_MOD + col0 + c4);
    }
    __syncthreads();
#pragma unroll
    for (int kk = 0; kk < 16; kk++) {
      float a[8], bv[8];
      *(float4*)&a[0] = *(float4*)&At[kk][ty * 8];
      *(float4*)&a[4] = *(float4*)&At[kk][ty * 8 + 4];
      *(float4*)&bv[0] = *(float4*)&Bt[kk][tx * 8];
      *(float4*)&bv[4] = *(float4*)&Bt[kk][tx * 8 + 4];
#pragma unroll
      for (int i2 = 0; i2 < 8; i2++)
#pragma unroll
        for (int j2 = 0; j2 < 8; j2++)
          acc[i2][j2] = fmaf(a[i2], bv[j2], acc[i2][j2]);
    }
    __syncthreads();
  }

  const int h = blockIdx.y;  // col0 == h*128 exactly (N-tile = one head)
#pragma unroll
  for (int er = 0; er < 8; er++) {
    int rt = row0 + ty * 8 + er;
    int bb = rt >> 11;
    int t = rt & (T_SEQ - 1);
    short8 ov;
#pragma unroll
    for (int ec = 0; ec < 8; ec++) ov[ec] = f2bf(acc[er][ec]);
    *(short8*)(dst + ((size_t)((bb * NH + h) * T_SEQ + t)) * HD + tx * 8) = ov;
  }
}

// ---------------- fp32 tiled GEMM: output projection + bias ----------------
__global__ __launch_bounds__(256, 2) void out_gemm(
    const float* __restrict__ A, const float* __restrict__ W,
    const float* __restrict__ bias, float* __restrict__ C) {
  __shared__ __align__(16) float At[16][132];
  __shared__ __align__(16) float Bt[16][132];
  const int tid = threadIdx.x;
  const int tx = tid & 15, ty = tid >> 4;
  const int row0 = blockIdx.x * 128;
  const int col0 = blockIdx.y * 128;

  float acc[8][8];
#pragma unroll
  for (int i = 0; i < 8; i++)
#pragma unroll
    for (int j = 0; j < 8; j++) acc[i][j] = 0.f;

  for (int k0 = 0; k0 < D_MOD; k0 += 16) {
#pragma unroll
    for (int i = 0; i < 2; i++) {
      int s = tid + i * 256;
      int r = s >> 2;
      int kq = (s & 3) << 2;
      float4 av = *(const float4*)(A + (size_t)(row0 + r) * D_MOD + k0 + kq);
      At[kq + 0][r] = av.x; At[kq + 1][r] = av.y;
      At[kq + 2][r] = av.z; At[kq + 3][r] = av.w;
    }
#pragma unroll
    for (int i = 0; i < 2; i++) {
      int s = tid + i * 256;
      int kk = s >> 5;
      int c4 = (s & 31) << 2;
      *(float4*)&Bt[kk][c4] =
          *(const float4*)(W + (size_t)(k0 + kk) * D_MOD + col0 + c4);
    }
    __syncthreads();
#pragma unroll
    for (int kk = 0; kk < 16; kk++) {
      float a[8], bv[8];
      *(float4*)&a[0] = *(float4*)&At[kk][ty * 8];
      *(float4*)&a[4] = *(float4*)&At[kk][ty * 8 + 4];
      *(float4*)&bv[0] = *(float4*)&Bt[kk][tx * 8];
      *(float4*)&bv[4] = *(float4*)&Bt[kk][tx * 8 + 4];
#pragma unroll
      for (int i2 = 0; i2 < 8; i2++)
#pragma unroll
        for (int j2 = 0; j2 < 8; j2++)
          acc[i2][j2] = fmaf(a[i2], bv[j2], acc[i2][j2]);
    }
    __syncthreads();
  }

#pragma unroll
  for (int er = 0; er < 8; er++) {
    int rt = row0 + ty * 8 + er;
#pragma unroll
    for (int ec = 0; ec < 8; ec += 4) {
      float4 ov;
      ov.x = acc[er][ec + 0] + bias[col0 + tx * 8 + ec + 0];
      ov.y = acc[er][ec + 1] + bias[col0 + tx * 8 + ec + 1];
      ov.z = acc[er][ec + 2] + bias[col0 + tx * 8 + ec + 2];
      ov.w = acc[er][ec + 3] + bias[col0 + tx * 8 + ec + 3];
      *(float4*)(C + (size_t)rt * D_MOD + col0 + tx * 8 + ec) = ov;
    }
  }
}

// ---------------- flash retention: QK^T * decay -> softmax -> PV -> GN -----
// grid = 512 blocks (qt 0..31, h 0..7, b 0..1), 256 threads = 4 waves.
// Each wave owns 16 q-rows (16x16x32 MFMA); j-tiles of 64 keys.
// Frag-major LDS layouts so every frag read is a linear ds_read_b128.
__global__ __launch_bounds__(256, 2) void attn_kernel(
    const short* __restrict__ qg, const short* __restrict__ kg,
    const short* __restrict__ vg, const float* __restrict__ dm_g,
    const float* __restrict__ gamma, const float* __restrict__ beta,
    float* __restrict__ y) {
  __shared__ __align__(16) short KT[4 * 4 * 64 * 8];  // [jb][kc][lane][8] 16KB
  __shared__ __align__(16) short VT[8 * 2 * 64 * 8];  // [cb][kc2][lane][8] 16KB
  __shared__ __align__(16) float P2[4][1024];         // [wave][kc2*512+lane*8+e]
  __shared__ float dm_s[T_SEQ];                       // 8KB

  const int tid = threadIdx.x;
  const int l = tid & 63, w = tid >> 6;
  const int lm = l & 15, lq = l >> 4;

  int qt = blockIdx.x & 31;
  const int h = (blockIdx.x >> 5) & 7;
  const int b = blockIdx.x >> 8;
  if (b) qt = 31 - qt;  // rough load balance across co-resident block pairs

  for (int i = tid; i < T_SEQ; i += 256) dm_s[i] = dm_g[i];

  const size_t hoff = (size_t)(b * NH + h) * T_SEQ * HD;
  const short* __restrict__ Qh = qg + hoff;
  const short* __restrict__ Kh = kg + hoff;
  const short* __restrict__ Vh = vg + hoff;

  // Q frags live in registers for the whole block row-tile
  short8 qf[4];
  {
    int row = qt * 64 + w * 16 + lm;
#pragma unroll
    for (int kc = 0; kc < 4; kc++)
      qf[kc] = *(const short8*)(Qh + (size_t)row * HD + kc * 32 + lq * 8);
  }

  f32x4 zero4 = {0.f, 0.f, 0.f, 0.f};
  f32x4 o[8];
#pragma unroll
  for (int cb = 0; cb < 8; cb++) o[cb] = zero4;
  float m_r[4], l_r[4];
#pragma unroll
  for (int r = 0; r < 4; r++) { m_r[r] = -1e30f; l_r[r] = 0.f; }

  const int i_row0 = qt * 64 + w * 16 + lq * 4;
  const int njt = qt + 1;

  __syncthreads();

  for (int jt = 0; jt < njt; jt++) {
    const int j0 = jt * 64;
    // ---- stage K tile (wave w stages jb = w), frag-major, linear b128 writes
#pragma unroll
    for (int kc = 0; kc < 4; kc++) {
      int jrow = j0 + w * 16 + lm;
      short8 kv = *(const short8*)(Kh + (size_t)jrow * HD + kc * 32 + lq * 8);
      *(short8*)&KT[((w * 4 + kc) * 64 + l) * 8] = kv;
    }
    // ---- stage V transposed into frag-major layout: pack 8 j's per column
    {
      const int d0 = (tid & 63) * 2;
#pragma unroll
      for (int pass = 0; pass < 2; pass++) {
        const int jl = (w + pass * 4) * 8;  // local j base
        unsigned vals[8];
#pragma unroll
        for (int jj = 0; jj < 8; jj++)
          vals[jj] = *(const unsigned*)(Vh + (size_t)(j0 + jl + jj) * HD + d0);
        const int kc2 = jl >> 5;
        const int bq = (jl >> 3) & 3;
#pragma unroll
        for (int dd = 0; dd < 2; dd++) {
          const int d = d0 + dd;
          short8 col;
#pragma unroll
          for (int jj = 0; jj < 8; jj++)
            col[jj] = (short)(dd ? (vals[jj] >> 16) : (vals[jj] & 0xffffu));
          *(short8*)&VT[(((d >> 4) * 2 + kc2) * 64 + bq * 16 + (d & 15)) * 8] =
              col;
        }
      }
    }
    __syncthreads();

    // ---- QK^T (A=Q 16x32 frags, B=K^T from frag-major LDS)
    float s[4][4];
#pragma unroll
    for (int jb = 0; jb < 4; jb++) {
      f32x4 acc = zero4;
#pragma unroll
      for (int kc = 0; kc < 4; kc++) {
        short8 kf = *(const short8*)&KT[((jb * 4 + kc) * 64 + l) * 8];
        acc = __builtin_amdgcn_mfma_f32_16x16x32_bf16(qf[kc], kf, acc, 0, 0, 0);
      }
      const int j = j0 + jb * 16 + lm;
#pragma unroll
      for (int r = 0; r < 4; r++) {
        int delta = (i_row0 + r) - j;
        s[jb][r] = (delta >= 0) ? acc[r] * dm_s[delta] : -__builtin_inff();
      }
    }

    // ---- online softmax (rows live in 16-lane groups; xor 1,2,4,8 reduce)
    float fac[4];
#pragma unroll
    for (int r = 0; r < 4; r++) {
      float mx = fmaxf(fmaxf(s[0][r], s[1][r]), fmaxf(s[2][r], s[3][r]));
      mx = fmaxf(mx, __shfl_xor(mx, 1));
      mx = fmaxf(mx, __shfl_xor(mx, 2));
      mx = fmaxf(mx, __shfl_xor(mx, 4));
      mx = fmaxf(mx, __shfl_xor(mx, 8));
      float mnew = fmaxf(m_r[r], mx);
      fac[r] = __expf(m_r[r] - mnew);
      m_r[r] = mnew;
    }
    float lsum[4] = {0.f, 0.f, 0.f, 0.f};
#pragma unroll
    for (int jb = 0; jb < 4; jb++) {
      const int jl2 = jb * 16 + lm;
      const int pbase = (jl2 >> 5) * 512 + ((jl2 & 31) >> 3) * 128 + (jl2 & 7);
#pragma unroll
      for (int r = 0; r < 4; r++) {
        float pv = __expf(s[jb][r] - m_r[r]);  // masked -> exp(-inf)=0
        lsum[r] += pv;
        P2[w][pbase + (lq * 4 + r) * 8] = pv;  // scatter into A-frag layout
      }
    }
#pragma unroll
    for (int r = 0; r < 4; r++) {
      float sm = lsum[r];
      sm += __shfl_xor(sm, 1); sm += __shfl_xor(sm, 2);
      sm += __shfl_xor(sm, 4); sm += __shfl_xor(sm, 8);
      l_r[r] = l_r[r] * fac[r] + sm;
    }
#pragma unroll
    for (int cb = 0; cb < 8; cb++)
#pragma unroll
      for (int r = 0; r < 4; r++) o[cb][r] *= fac[r];

    // ---- PV (A=P from wave-private LDS roundtrip, B=V^T frag-major)
#pragma unroll
    for (int kc2 = 0; kc2 < 2; kc2++) {
      f32x4 pa0 = *(const f32x4*)&P2[w][kc2 * 512 + l * 8];
      f32x4 pa1 = *(const f32x4*)&P2[w][kc2 * 512 + l * 8 + 4];
      short8 pb;
#pragma unroll
      for (int e = 0; e < 4; e++) {
        pb[e] = f2bf(pa0[e]);
        pb[e + 4] = f2bf(pa1[e]);
      }
#pragma unroll
      for (int cb = 0; cb < 8; cb++) {
        short8 vf = *(const short8*)&VT[((cb * 2 + kc2) * 64 + l) * 8];
        o[cb] = __builtin_amdgcn_mfma_f32_16x16x32_bf16(pb, vf, o[cb], 0, 0, 0);
      }
    }
    __syncthreads();
  }

  // ---- epilogue: 1/l, per-head GroupNorm, gamma/beta, write y (fp32)
  float mu[4], rstd[4];
#pragma unroll
  for (int r = 0; r < 4; r++) {
    float inv = 1.0f / l_r[r];
    float sum = 0.f, sq = 0.f;
#pragma unroll
    for (int cb = 0; cb < 8; cb++) {
      float v2 = o[cb][r] * inv;
      o[cb][r] = v2;
      sum += v2;
      sq += v2 * v2;
    }
    sum += __shfl_xor(sum, 1); sum += __shfl_xor(sum, 2);
    sum += __shfl_xor(sum, 4); sum += __shfl_xor(sum, 8);
    sq += __shfl_xor(sq, 1); sq += __shfl_xor(sq, 2);
    sq += __shfl_xor(sq, 4); sq += __shfl_xor(sq, 8);
    float m2 = sum * (1.f / 128.f);
    mu[r] = m2;
    rstd[r] = rsqrtf(sq * (1.f / 128.f) - m2 * m2 + 1e-5f);
  }
  const int trow = qt * 64 + w * 16 + lq * 4;
#pragma unroll
  for (int cb = 0; cb < 8; cb++) {
    const int dcol = h * HD + cb * 16 + lm;
    const float g = gamma[dcol], be = beta[dcol];
#pragma unroll
    for (int r = 0; r < 4; r++) {
      float val = (o[cb][r] - mu[r]) * rstd[r] * g + be;
      y[(size_t)(b * T_SEQ + trow + r) * D_MOD + dcol] = val;
    }
  }
}

// ---------------------------------------------------------------------------
extern "C" void kernel_launch(void* const* d_in, const int* in_sizes, int n_in,
                              void* d_out, int out_size, void* d_ws,
                              size_t ws_size, hipStream_t stream) {
  const float* x     = (const float*)d_in[0];
  const float* Wq    = (const float*)d_in[1];
  const float* Wk    = (const float*)d_in[2];
  const float* Wv    = (const float*)d_in[3];
  const float* Wo    = (const float*)d_in[4];
  const float* bo    = (const float*)d_in[5];
  const float* theta = (const float*)d_in[6];
  const float* gamma = (const float*)d_in[7];
  const float* beta  = (const float*)d_in[8];
  float* out = (float*)d_out;

  char* ws = (char*)d_ws;
  short* qb = (short*)(ws + (size_t)0);                   // 8 MB bf16 (B,H,T,HD)
  short* kb = (short*)(ws + (size_t)8 * 1024 * 1024);     // 8 MB
  short* vb = (short*)(ws + (size_t)16 * 1024 * 1024);    // 8 MB
  float* y  = (float*)(ws + (size_t)24 * 1024 * 1024);    // 16 MB fp32 (B*T, D)
  float* dm = (float*)(ws + (size_t)40 * 1024 * 1024);    // 8 KB decay table

  decay_kernel<<<dim3(8), dim3(256), 0, stream>>>(theta, dm);
  qkv_gemm<<<dim3(32, 8, 3), dim3(256), 0, stream>>>(x, Wq, Wk, Wv, qb, kb, vb);
  attn_kernel<<<dim3(512), dim3(256), 0, stream>>>(qb, kb, vb, dm, gamma, beta, y);
  out_gemm<<<dim3(32, 8), dim3(256), 0, stream>>>(y, Wo, bo, out);
}

// Round 2
// 248.919 us; speedup vs baseline: 2.3955x; 2.3955x over previous
//
#include <hip/hip_runtime.h>

#define B_SZ  2
#define T_SEQ 2048
#define D_MOD 1024
#define NH    8
#define HD    128

typedef __attribute__((ext_vector_type(8))) short short8;   // 8 x bf16 frag
typedef __attribute__((ext_vector_type(4))) float f32x4;    // mfma accumulator

__device__ __forceinline__ short f2bf(float f) {
  unsigned u = __float_as_uint(f);
  unsigned r = u + 0x7fffu + ((u >> 16) & 1u);   // RNE
  return (short)(r >> 16);
}

__device__ __forceinline__ void gld_lds16(const short* g, short* l) {
  __builtin_amdgcn_global_load_lds(
      (const __attribute__((address_space(1))) void*)g,
      (__attribute__((address_space(3))) void*)l, 16, 0, 0);
}

// ---------------- decay table: dm[n] = mean_h exp(-theta_h*n) / sqrt(HD) ----
__global__ void decay_kernel(const float* __restrict__ theta,
                             float* __restrict__ dm) {
  int n = blockIdx.x * 256 + threadIdx.x;
  if (n >= T_SEQ) return;
  float nf = (float)n;
  float s = 0.f;
#pragma unroll
  for (int h = 0; h < NH; h++) s += __expf(-theta[h] * nf);
  dm[n] = s * (0.08838834764831845f / 8.0f);  // (1/sqrt(128)) * (1/H)
}

// ---------------- x fp32 -> bf16 (same layout) -----------------------------
__global__ __launch_bounds__(256) void cvt_x(const float* __restrict__ x,
                                             short* __restrict__ xb) {
  int i = (blockIdx.x * 256 + threadIdx.x) * 8;
  float4 a = *(const float4*)(x + i);
  float4 b = *(const float4*)(x + i + 4);
  short8 o;
  o[0] = f2bf(a.x); o[1] = f2bf(a.y); o[2] = f2bf(a.z); o[3] = f2bf(a.w);
  o[4] = f2bf(b.x); o[5] = f2bf(b.y); o[6] = f2bf(b.z); o[7] = f2bf(b.w);
  *(short8*)(xb + i) = o;
}

// ---------------- W (K,N) fp32 -> W^T (N,K) bf16, 32x32 LDS transpose ------
__global__ __launch_bounds__(256) void cvt_w(const float* __restrict__ Wq,
                                             const float* __restrict__ Wk,
                                             const float* __restrict__ Wv,
                                             const float* __restrict__ Wo,
                                             short* __restrict__ wt) {
  __shared__ float t[32][33];
  const int z = blockIdx.z;
  const float* __restrict__ W = (z == 0) ? Wq : (z == 1) ? Wk : (z == 2) ? Wv : Wo;
  short* __restrict__ dst = wt + (size_t)z * D_MOD * D_MOD;
  const int k0 = blockIdx.x * 32, n0 = blockIdx.y * 32;
  const int tx = threadIdx.x & 31, ty = threadIdx.x >> 5;
#pragma unroll
  for (int i = 0; i < 4; i++)
    t[ty * 4 + i][tx] = W[(size_t)(k0 + ty * 4 + i) * D_MOD + n0 + tx];
  __syncthreads();
#pragma unroll
  for (int i = 0; i < 4; i++)
    dst[(size_t)(n0 + ty * 4 + i) * D_MOD + k0 + tx] = f2bf(t[tx][ty * 4 + i]);
}

// ---------------- bf16 MFMA GEMM (m97 structure): QKV projections ----------
// C(4096x128 per head) = xb(4096x1024) @ Wt(h-cols,1024)^T; out bf16 (B,H,T,HD)
__global__ __launch_bounds__(256, 3) void gemm_qkv(
    const short* __restrict__ xb, const short* __restrict__ wt,
    short* __restrict__ qb, short* __restrict__ kb, short* __restrict__ vb) {
  __shared__ __align__(16) short As[128 * 32];   // [row][k] row-major, 8KB
  __shared__ __align__(16) short Bs[128 * 32];   // [col][k] (W^T rows), 8KB
  const int tid = threadIdx.x;
  const int l = tid & 63, w = tid >> 6;
  const int wr = w >> 1, wc = w & 1;
  const int row0 = blockIdx.x * 128;
  const int h = blockIdx.y;
  const int col0 = h * 128;
  const short* __restrict__ Wt = wt + (size_t)blockIdx.z * D_MOD * D_MOD;
  short* __restrict__ dst = (blockIdx.z == 0) ? qb : (blockIdx.z == 1) ? kb : vb;

  f32x4 acc[4][4];
#pragma unroll
  for (int m = 0; m < 4; m++)
#pragma unroll
    for (int n = 0; n < 4; n++) acc[m][n] = (f32x4){0.f, 0.f, 0.f, 0.f};

  const int cA = w * 2;            // this wave's two 1KB LDS chunks
  const int sr = l >> 2;           // row within chunk (16 rows/chunk)
  const int skq = (l & 3) << 3;    // k element offset (4x8 elems per row)

#pragma unroll
  for (int i = 0; i < 2; i++) {
    int c = cA + i;
    gld_lds16(xb + (size_t)(row0 + c * 16 + sr) * D_MOD + skq, As + c * 512);
    gld_lds16(Wt + (size_t)(col0 + c * 16 + sr) * D_MOD + skq, Bs + c * 512);
  }
  for (int ks = 0; ks < 32; ks++) {
    __syncthreads();  // drains vmcnt(0): staged tile visible
    short8 af[4], bf[4];
#pragma unroll
    for (int m = 0; m < 4; m++)
      af[m] = *(const short8*)&As[(wr * 64 + m * 16 + (l & 15)) * 32 + (l >> 4) * 8];
#pragma unroll
    for (int n = 0; n < 4; n++)
      bf[n] = *(const short8*)&Bs[(wc * 64 + n * 16 + (l & 15)) * 32 + (l >> 4) * 8];
#pragma unroll
    for (int m = 0; m < 4; m++)
#pragma unroll
      for (int n = 0; n < 4; n++)
        acc[m][n] =
            __builtin_amdgcn_mfma_f32_16x16x32_bf16(af[m], bf[n], acc[m][n], 0, 0, 0);
    __syncthreads();  // LDS consumed, safe to overwrite
    if (ks < 31) {
      const int k0 = (ks + 1) * 32;
#pragma unroll
      for (int i = 0; i < 2; i++) {
        int c = cA + i;
        gld_lds16(xb + (size_t)(row0 + c * 16 + sr) * D_MOD + k0 + skq, As + c * 512);
        gld_lds16(Wt + (size_t)(col0 + c * 16 + sr) * D_MOD + k0 + skq, Bs + c * 512);
      }
    }
  }
  // epilogue: C row=(l>>4)*4+j, col=l&15 (m89 layout); write (B,H,T,HD) bf16
#pragma unroll
  for (int m = 0; m < 4; m++) {
#pragma unroll
    for (int j = 0; j < 4; j++) {
      int row = row0 + wr * 64 + m * 16 + (l >> 4) * 4 + j;
      int bb = row >> 11, t = row & (T_SEQ - 1);
      size_t base = ((size_t)(bb * NH + h) * T_SEQ + t) * HD + wc * 64 + (l & 15);
#pragma unroll
      for (int n = 0; n < 4; n++) dst[base + n * 16] = f2bf(acc[m][n][j]);
    }
  }
}

// ---------------- bf16 MFMA GEMM: output projection + bias (fp32 out) ------
__global__ __launch_bounds__(256, 3) void gemm_out(
    const short* __restrict__ yb, const short* __restrict__ wot,
    const float* __restrict__ bias, float* __restrict__ out) {
  __shared__ __align__(16) short As[128 * 32];
  __shared__ __align__(16) short Bs[128 * 32];
  const int tid = threadIdx.x;
  const int l = tid & 63, w = tid >> 6;
  const int wr = w >> 1, wc = w & 1;
  const int row0 = blockIdx.x * 128;
  const int col0 = blockIdx.y * 128;

  f32x4 acc[4][4];
#pragma unroll
  for (int m = 0; m < 4; m++)
#pragma unroll
    for (int n = 0; n < 4; n++) acc[m][n] = (f32x4){0.f, 0.f, 0.f, 0.f};

  const int cA = w * 2;
  const int sr = l >> 2;
  const int skq = (l & 3) << 3;

#pragma unroll
  for (int i = 0; i < 2; i++) {
    int c = cA + i;
    gld_lds16(yb + (size_t)(row0 + c * 16 + sr) * D_MOD + skq, As + c * 512);
    gld_lds16(wot + (size_t)(col0 + c * 16 + sr) * D_MOD + skq, Bs + c * 512);
  }
  for (int ks = 0; ks < 32; ks++) {
    __syncthreads();
    short8 af[4], bf[4];
#pragma unroll
    for (int m = 0; m < 4; m++)
      af[m] = *(const short8*)&As[(wr * 64 + m * 16 + (l & 15)) * 32 + (l >> 4) * 8];
#pragma unroll
    for (int n = 0; n < 4; n++)
      bf[n] = *(const short8*)&Bs[(wc * 64 + n * 16 + (l & 15)) * 32 + (l >> 4) * 8];
#pragma unroll
    for (int m = 0; m < 4; m++)
#pragma unroll
      for (int n = 0; n < 4; n++)
        acc[m][n] =
            __builtin_amdgcn_mfma_f32_16x16x32_bf16(af[m], bf[n], acc[m][n], 0, 0, 0);
    __syncthreads();
    if (ks < 31) {
      const int k0 = (ks + 1) * 32;
#pragma unroll
      for (int i = 0; i < 2; i++) {
        int c = cA + i;
        gld_lds16(yb + (size_t)(row0 + c * 16 + sr) * D_MOD + k0 + skq, As + c * 512);
        gld_lds16(wot + (size_t)(col0 + c * 16 + sr) * D_MOD + k0 + skq, Bs + c * 512);
      }
    }
  }
#pragma unroll
  for (int m = 0; m < 4; m++) {
#pragma unroll
    for (int j = 0; j < 4; j++) {
      int row = row0 + wr * 64 + m * 16 + (l >> 4) * 4 + j;
#pragma unroll
      for (int n = 0; n < 4; n++) {
        int col = col0 + wc * 64 + n * 16 + (l & 15);
        out[(size_t)row * D_MOD + col] = acc[m][n][j] + bias[col];
      }
    }
  }
}

// ---------------- flash retention: QK^T * decay -> softmax -> PV -> GN -----
// grid = 512 blocks (qt 0..31, h 0..7, b 0..1), 256 threads = 4 waves.
__global__ __launch_bounds__(256, 2) void attn_kernel(
    const short* __restrict__ qg, const short* __restrict__ kg,
    const short* __restrict__ vg, const float* __restrict__ dm_g,
    const float* __restrict__ gamma, const float* __restrict__ beta,
    short* __restrict__ yb) {
  __shared__ __align__(16) short KT[4 * 4 * 64 * 8];  // [jb][kc][lane][8] 16KB
  __shared__ __align__(16) short VT[8 * 2 * 64 * 8];  // [cb][kc2][lane][8] 16KB
  __shared__ __align__(16) float P2[4][1024];         // [wave][kc2*512+lane*8+e]
  __shared__ float dm_s[T_SEQ];                       // 8KB

  const int tid = threadIdx.x;
  const int l = tid & 63, w = tid >> 6;
  const int lm = l & 15, lq = l >> 4;

  int qt = blockIdx.x & 31;
  const int h = (blockIdx.x >> 5) & 7;
  const int b = blockIdx.x >> 8;
  if (b) qt = 31 - qt;  // rough load balance across co-resident block pairs

  for (int i = tid; i < T_SEQ; i += 256) dm_s[i] = dm_g[i];

  const size_t hoff = (size_t)(b * NH + h) * T_SEQ * HD;
  const short* __restrict__ Qh = qg + hoff;
  const short* __restrict__ Kh = kg + hoff;
  const short* __restrict__ Vh = vg + hoff;

  short8 qf[4];
  {
    int row = qt * 64 + w * 16 + lm;
#pragma unroll
    for (int kc = 0; kc < 4; kc++)
      qf[kc] = *(const short8*)(Qh + (size_t)row * HD + kc * 32 + lq * 8);
  }

  f32x4 zero4 = {0.f, 0.f, 0.f, 0.f};
  f32x4 o[8];
#pragma unroll
  for (int cb = 0; cb < 8; cb++) o[cb] = zero4;
  float m_r[4], l_r[4];
#pragma unroll
  for (int r = 0; r < 4; r++) { m_r[r] = -1e30f; l_r[r] = 0.f; }

  const int i_row0 = qt * 64 + w * 16 + lq * 4;
  const int njt = qt + 1;

  __syncthreads();

  for (int jt = 0; jt < njt; jt++) {
    const int j0 = jt * 64;
#pragma unroll
    for (int kc = 0; kc < 4; kc++) {
      int jrow = j0 + w * 16 + lm;
      short8 kv = *(const short8*)(Kh + (size_t)jrow * HD + kc * 32 + lq * 8);
      *(short8*)&KT[((w * 4 + kc) * 64 + l) * 8] = kv;
    }
    {
      const int d0 = (tid & 63) * 2;
#pragma unroll
      for (int pass = 0; pass < 2; pass++) {
        const int jl = (w + pass * 4) * 8;
        unsigned vals[8];
#pragma unroll
        for (int jj = 0; jj < 8; jj++)
          vals[jj] = *(const unsigned*)(Vh + (size_t)(j0 + jl + jj) * HD + d0);
        const int kc2 = jl >> 5;
        const int bq = (jl >> 3) & 3;
#pragma unroll
        for (int dd = 0; dd < 2; dd++) {
          const int d = d0 + dd;
          short8 col;
#pragma unroll
          for (int jj = 0; jj < 8; jj++)
            col[jj] = (short)(dd ? (vals[jj] >> 16) : (vals[jj] & 0xffffu));
          *(short8*)&VT[(((d >> 4) * 2 + kc2) * 64 + bq * 16 + (d & 15)) * 8] =
              col;
        }
      }
    }
    __syncthreads();

    float s[4][4];
#pragma unroll
    for (int jb = 0; jb < 4; jb++) {
      f32x4 acc = zero4;
#pragma unroll
      for (int kc = 0; kc < 4; kc++) {
        short8 kf = *(const short8*)&KT[((jb * 4 + kc) * 64 + l) * 8];
        acc = __builtin_amdgcn_mfma_f32_16x16x32_bf16(qf[kc], kf, acc, 0, 0, 0);
      }
      const int j = j0 + jb * 16 + lm;
#pragma unroll
      for (int r = 0; r < 4; r++) {
        int delta = (i_row0 + r) - j;
        s[jb][r] = (delta >= 0) ? acc[r] * dm_s[delta] : -__builtin_inff();
      }
    }

    float fac[4];
#pragma unroll
    for (int r = 0; r < 4; r++) {
      float mx = fmaxf(fmaxf(s[0][r], s[1][r]), fmaxf(s[2][r], s[3][r]));
      mx = fmaxf(mx, __shfl_xor(mx, 1));
      mx = fmaxf(mx, __shfl_xor(mx, 2));
      mx = fmaxf(mx, __shfl_xor(mx, 4));
      mx = fmaxf(mx, __shfl_xor(mx, 8));
      float mnew = fmaxf(m_r[r], mx);
      fac[r] = __expf(m_r[r] - mnew);
      m_r[r] = mnew;
    }
    float lsum[4] = {0.f, 0.f, 0.f, 0.f};
#pragma unroll
    for (int jb = 0; jb < 4; jb++) {
      const int jl2 = jb * 16 + lm;
      const int pbase = (jl2 >> 5) * 512 + ((jl2 & 31) >> 3) * 128 + (jl2 & 7);
#pragma unroll
      for (int r = 0; r < 4; r++) {
        float pv = __expf(s[jb][r] - m_r[r]);
        lsum[r] += pv;
        P2[w][pbase + (lq * 4 + r) * 8] = pv;
      }
    }
#pragma unroll
    for (int r = 0; r < 4; r++) {
      float sm = lsum[r];
      sm += __shfl_xor(sm, 1); sm += __shfl_xor(sm, 2);
      sm += __shfl_xor(sm, 4); sm += __shfl_xor(sm, 8);
      l_r[r] = l_r[r] * fac[r] + sm;
    }
#pragma unroll
    for (int cb = 0; cb < 8; cb++)
#pragma unroll
      for (int r = 0; r < 4; r++) o[cb][r] *= fac[r];

#pragma unroll
    for (int kc2 = 0; kc2 < 2; kc2++) {
      f32x4 pa0 = *(const f32x4*)&P2[w][kc2 * 512 + l * 8];
      f32x4 pa1 = *(const f32x4*)&P2[w][kc2 * 512 + l * 8 + 4];
      short8 pb;
#pragma unroll
      for (int e = 0; e < 4; e++) {
        pb[e] = f2bf(pa0[e]);
        pb[e + 4] = f2bf(pa1[e]);
      }
#pragma unroll
      for (int cb = 0; cb < 8; cb++) {
        short8 vf = *(const short8*)&VT[((cb * 2 + kc2) * 64 + l) * 8];
        o[cb] = __builtin_amdgcn_mfma_f32_16x16x32_bf16(pb, vf, o[cb], 0, 0, 0);
      }
    }
    __syncthreads();
  }

  float mu[4], rstd[4];
#pragma unroll
  for (int r = 0; r < 4; r++) {
    float inv = 1.0f / l_r[r];
    float sum = 0.f, sq = 0.f;
#pragma unroll
    for (int cb = 0; cb < 8; cb++) {
      float v2 = o[cb][r] * inv;
      o[cb][r] = v2;
      sum += v2;
      sq += v2 * v2;
    }
    sum += __shfl_xor(sum, 1); sum += __shfl_xor(sum, 2);
    sum += __shfl_xor(sum, 4); sum += __shfl_xor(sum, 8);
    sq += __shfl_xor(sq, 1); sq += __shfl_xor(sq, 2);
    sq += __shfl_xor(sq, 4); sq += __shfl_xor(sq, 8);
    float m2 = sum * (1.f / 128.f);
    mu[r] = m2;
    rstd[r] = rsqrtf(sq * (1.f / 128.f) - m2 * m2 + 1e-5f);
  }
  const int trow = qt * 64 + w * 16 + lq * 4;
#pragma unroll
  for (int cb = 0; cb < 8; cb++) {
    const int dcol = h * HD + cb * 16 + lm;
    const float g = gamma[dcol], be = beta[dcol];
#pragma unroll
    for (int r = 0; r < 4; r++) {
      float val = (o[cb][r] - mu[r]) * rstd[r] * g + be;
      yb[(size_t)(b * T_SEQ + trow + r) * D_MOD + dcol] = f2bf(val);
    }
  }
}

// ---------------------------------------------------------------------------
extern "C" void kernel_launch(void* const* d_in, const int* in_sizes, int n_in,
                              void* d_out, int out_size, void* d_ws,
                              size_t ws_size, hipStream_t stream) {
  const float* x     = (const float*)d_in[0];
  const float* Wq    = (const float*)d_in[1];
  const float* Wk    = (const float*)d_in[2];
  const float* Wv    = (const float*)d_in[3];
  const float* Wo    = (const float*)d_in[4];
  const float* bo    = (const float*)d_in[5];
  const float* theta = (const float*)d_in[6];
  const float* gamma = (const float*)d_in[7];
  const float* beta  = (const float*)d_in[8];
  float* out = (float*)d_out;

  char* ws = (char*)d_ws;
  const size_t MB = 1024 * 1024;
  short* qb = (short*)(ws + 0 * MB);    // 8 MB bf16 (B,H,T,HD)
  short* kb = (short*)(ws + 8 * MB);    // 8 MB
  short* vb = (short*)(ws + 16 * MB);   // 8 MB
  short* yb = (short*)(ws + 24 * MB);   // 8 MB bf16 (B*T, D)
  short* xb = (short*)(ws + 32 * MB);   // 8 MB bf16 (B*T, D)
  short* wt = (short*)(ws + 40 * MB);   // 8 MB: 4x (1024,1024) bf16 W^T
  float* dm = (float*)(ws + 48 * MB);   // 8 KB decay table

  decay_kernel<<<dim3(8), dim3(256), 0, stream>>>(theta, dm);
  cvt_x<<<dim3(2048), dim3(256), 0, stream>>>(x, xb);
  cvt_w<<<dim3(32, 32, 4), dim3(256), 0, stream>>>(Wq, Wk, Wv, Wo, wt);
  gemm_qkv<<<dim3(32, 8, 3), dim3(256), 0, stream>>>(xb, wt, qb, kb, vb);
  attn_kernel<<<dim3(512), dim3(256), 0, stream>>>(qb, kb, vb, dm, gamma, beta, yb);
  gemm_out<<<dim3(32, 8), dim3(256), 0, stream>>>(
      yb, wt + (size_t)3 * D_MOD * D_MOD, bo, out);
}